// Round 9
// baseline (760.733 us; speedup 1.0000x reference)
//
#include <hip/hip_runtime.h>
#include <hip/hip_bf16.h>

// GCN 2-layer forward on MI355X — round 9.
// Build: coarse counting sort only (edges bucket-ordered in `pool`); the fine
// per-node sort, CSR, rowptr and per-node gather walks are DELETED. Aggregation
// is edge-parallel per bucket in LDS (acc[512][17] f32, ds_add_f32), which is
// conflict-light and fully streaming. dinv comes from a per-bucket wsum pass.
// gemm1: no-LDS register GEMM (x full-line 64B/lane loads, W1 s_load), now
// split-K=4 for ~24 waves/CU (round-6/8 had ~9-12: latency-bound at 78us).
// Inputs: x[N,512] f32, edge_index[2,E] int32, edge_weight[E] f32,
//         W1[512,16], b1[16], W2[16,10], b2[10]
// Outputs (concat): log_softmax(logits)[N,10], x1[N,16]

#define NF1 16   // hidden
#define NF2 10   // classes
#define FIN 512
#define EPB 8192 // edges per coarse block (256 thr * 32)
#define SK  4    // gemm1 split-K factor

typedef unsigned long long ull;

// ---------- A: coarse count (col>>9) into per-block histograms ----------
// blkhist layout TRANSPOSED: blkhist[bucket*NBLK + blk].
__global__ __launch_bounds__(256) void coarse_count_kernel(const int* __restrict__ col,
                                                           int* __restrict__ blkhist,
                                                           int E, int NB, int NBLK) {
    __shared__ int lh[256];
    int t = threadIdx.x;
    lh[t] = 0;
    __syncthreads();
    int base = blockIdx.x * EPB;
    int cnt = min(EPB, E - base);
    for (int i = t; i < cnt; i += 256)
        atomicAdd(&lh[col[base + i] >> 9], 1);
    __syncthreads();
    if (t < NB) blkhist[t * NBLK + blockIdx.x] = lh[t];
}

// ---------- B1: per-bucket exclusive scan over blocks (parallel) ----------
__global__ __launch_bounds__(512) void bucket_scan_kernel(int* __restrict__ blkhist,
                                                          int* __restrict__ btot,
                                                          int NBLK) {
    __shared__ int s[512];
    int t = threadIdx.x;
    int* p = blkhist + (size_t)blockIdx.x * NBLK;
    int carry = 0;
    for (int base = 0; base < NBLK; base += 512) {
        int idx = base + t;
        int v = (idx < NBLK) ? p[idx] : 0;
        s[t] = v;
        __syncthreads();
        for (int off = 1; off < 512; off <<= 1) {
            int u = (t >= off) ? s[t - off] : 0;
            __syncthreads();
            s[t] += u;
            __syncthreads();
        }
        if (idx < NBLK) p[idx] = s[t] - v + carry;
        carry += s[511];
        __syncthreads();
    }
    if (t == 0) btot[blockIdx.x] = carry;
}

// ---------- B2: scan bucket totals -> bbase ----------
__global__ __launch_bounds__(256) void base_scan_kernel(const int* __restrict__ btot,
                                                        int* __restrict__ bbase,
                                                        int NB, int E) {
    __shared__ int s[256];
    int t = threadIdx.x;
    int v = (t < NB) ? btot[t] : 0;
    s[t] = v;
    __syncthreads();
    for (int off = 1; off < 256; off <<= 1) {
        int u = (t >= off) ? s[t - off] : 0;
        __syncthreads();
        s[t] += u;
        __syncthreads();
    }
    if (t < NB) bbase[t] = s[t] - v;
    if (t == 0) bbase[NB] = E;
}

// ---------- C: coarse scatter into bucket-ordered pool ----------
// pool entry: hi32 = (c9<<20)|row, lo32 = weight bits   (row < 2^20)
__global__ __launch_bounds__(256) void coarse_scatter_kernel(const int* __restrict__ row,
                                                             const int* __restrict__ col,
                                                             const float* __restrict__ ew,
                                                             const int* __restrict__ blkhist,
                                                             const int* __restrict__ bbase,
                                                             ull* __restrict__ pool,
                                                             int E, int NB, int NBLK) {
    __shared__ int cur[256];
    int t = threadIdx.x;
    if (t < NB) cur[t] = blkhist[t * NBLK + blockIdx.x] + bbase[t];
    __syncthreads();
    int base = blockIdx.x * EPB;
    int cnt = min(EPB, E - base);
    for (int i = t; i < cnt; i += 256) {
        int e = base + i;
        int c = col[e], r = row[e];
        float w = ew[e];
        int b = c >> 9, c9 = c & 511;
        int pos = atomicAdd(&cur[b], 1);
        pool[pos] = ((ull)((((unsigned)c9) << 20) | (unsigned)r) << 32) | (ull)__float_as_uint(w);
    }
}

// ---------- D: per-bucket weight-sum -> dinv ----------
__global__ __launch_bounds__(1024) void bucket_deg_kernel(const ull* __restrict__ pool,
                                                          const int* __restrict__ bbase,
                                                          float* __restrict__ dinv, int N) {
    __shared__ float wsum[512];
    int t = threadIdx.x;
    int b = blockIdx.x;
    if (t < 512) wsum[t] = 0.0f;
    __syncthreads();
    int bb = bbase[b], be = bbase[b + 1];
    for (int i = bb + t; i < be; i += 1024) {
        ull p = pool[i];
        int c9 = ((unsigned)(p >> 32) >> 20) & 511;
        atomicAdd(&wsum[c9], __uint_as_float((unsigned)p));
    }
    __syncthreads();
    int c = (b << 9) + t;
    if (t < 512 && c < N) dinv[c] = rsqrtf(1.0f + wsum[t]);   // deg = self(1)+sum(w)
}

// ---------- GEMM1 (split-K=4, no LDS, full-line loads): part[q][row][f] ----------
__device__ __forceinline__ void fma16(float av, const float* __restrict__ wrow,
                                      float* __restrict__ acc) {
#pragma unroll
    for (int f = 0; f < NF1; f++) acc[f] = fmaf(av, wrow[f], acc[f]);
}

__global__ __launch_bounds__(256) void gemm1_kernel(const float* __restrict__ x,
                                                    const float* __restrict__ W1,
                                                    float* __restrict__ part,
                                                    int N, int nbRow) {
    int b = blockIdx.x;
    int q = b / nbRow;                 // K-quarter 0..3
    int rb = b - q * nbRow;
    int row = rb * 256 + threadIdx.x;
    if (row >= N) return;
    const int k0 = q * (FIN / SK);     // 128 per quarter

    float acc[NF1];
#pragma unroll
    for (int f = 0; f < NF1; f++) acc[f] = 0.0f;

    const float* xr = x + (size_t)row * FIN + k0;
    const float* wp = W1 + (size_t)k0 * NF1;

#pragma unroll 2
    for (int k = 0; k < FIN / SK; k += 16) {
        const float4* xp = reinterpret_cast<const float4*>(xr + k);
        float4 a0 = xp[0];
        float4 a1 = xp[1];
        float4 a2 = xp[2];
        float4 a3 = xp[3];
        const float* wk = wp + (size_t)k * NF1;
        fma16(a0.x, wk + 0 * NF1, acc);
        fma16(a0.y, wk + 1 * NF1, acc);
        fma16(a0.z, wk + 2 * NF1, acc);
        fma16(a0.w, wk + 3 * NF1, acc);
        fma16(a1.x, wk + 4 * NF1, acc);
        fma16(a1.y, wk + 5 * NF1, acc);
        fma16(a1.z, wk + 6 * NF1, acc);
        fma16(a1.w, wk + 7 * NF1, acc);
        fma16(a2.x, wk + 8 * NF1, acc);
        fma16(a2.y, wk + 9 * NF1, acc);
        fma16(a2.z, wk + 10 * NF1, acc);
        fma16(a2.w, wk + 11 * NF1, acc);
        fma16(a3.x, wk + 12 * NF1, acc);
        fma16(a3.y, wk + 13 * NF1, acc);
        fma16(a3.z, wk + 14 * NF1, acc);
        fma16(a3.w, wk + 15 * NF1, acc);
    }

    float* pp = part + ((size_t)q * N + row) * NF1;
#pragma unroll
    for (int qq = 0; qq < 4; qq++) {
        float4 o = make_float4(acc[4 * qq], acc[4 * qq + 1], acc[4 * qq + 2], acc[4 * qq + 3]);
        *reinterpret_cast<float4*>(pp + 4 * qq) = o;
    }
}

// ---------- combine split-K partials, fold dinv: hs = dinv[row]*(p0+p1+p2+p3) ----------
__global__ __launch_bounds__(256) void combine_scale_kernel(const float* __restrict__ part,
                                                            const float* __restrict__ dinv,
                                                            float* __restrict__ hs, int N) {
    int i4 = blockIdx.x * 256 + threadIdx.x;     // float4 index
    int total = N * NF1 / 4;
    if (i4 >= total) return;
    int rowIdx = i4 >> 2;                        // 4 float4 per row
    const float4* p0 = reinterpret_cast<const float4*>(part);
    const float4* p1 = reinterpret_cast<const float4*>(part + (size_t)1 * N * NF1);
    const float4* p2 = reinterpret_cast<const float4*>(part + (size_t)2 * N * NF1);
    const float4* p3 = reinterpret_cast<const float4*>(part + (size_t)3 * N * NF1);
    float4 a = p0[i4], b = p1[i4], c = p2[i4], d4 = p3[i4];
    float d = dinv[rowIdx];
    float4 o = make_float4(d * (a.x + b.x + c.x + d4.x), d * (a.y + b.y + c.y + d4.y),
                           d * (a.z + b.z + c.z + d4.z), d * (a.w + b.w + c.w + d4.w));
    reinterpret_cast<float4*>(hs)[i4] = o;
}

// ---------- agg layer 1: x1[c] = b1 + di*( sum_w w*hs[r] + hs[c] )  per bucket in LDS ----------
__global__ __launch_bounds__(1024) void agg1_kernel(const ull* __restrict__ pool,
                                                    const int* __restrict__ bbase,
                                                    const float* __restrict__ dinv,
                                                    const float* __restrict__ hs,
                                                    const float* __restrict__ b1,
                                                    float* __restrict__ x1, int N) {
    __shared__ float acc[512 * 17];              // stride 17: conflict-light
    int t = threadIdx.x;
    int b = blockIdx.x;
    for (int i = t; i < 512 * 17; i += 1024) acc[i] = 0.0f;
    __syncthreads();
    int bb = bbase[b], be = bbase[b + 1];
    int f = t & 15;
    int eg = t >> 4;                             // 64 edge-groups
    for (int i = bb + eg; i < be; i += 64) {
        ull p = pool[i];
        unsigned hi = (unsigned)(p >> 32);
        int c9 = (hi >> 20) & 511;
        int r = hi & 0xFFFFF;
        float w = __uint_as_float((unsigned)p);
        float hv = hs[(size_t)r * NF1 + f];      // 16 lanes: coalesced 64B
        atomicAdd(&acc[c9 * 17 + f], w * hv);
    }
    __syncthreads();
    for (int idx = t; idx < 512 * NF1; idx += 1024) {
        int c9 = idx >> 4, ff = idx & 15;
        int node = (b << 9) + c9;
        if (node < N) {
            float di = dinv[node];
            x1[(size_t)node * NF1 + ff] =
                b1[ff] + di * (acc[c9 * 17 + ff] + hs[(size_t)node * NF1 + ff]);
        }
    }
}

// ---------- GEMM2: hh = dinv[j] * (relu(x1[j]) @ W2) ----------
__global__ __launch_bounds__(256) void gemm2_kernel(const float* __restrict__ x1,
                                                    const float* __restrict__ W2,
                                                    const float* __restrict__ dinv,
                                                    float* __restrict__ hh, int N) {
    int j = blockIdx.x * 256 + threadIdx.x;
    if (j >= N) return;
    float xr[NF1];
#pragma unroll
    for (int f = 0; f < NF1; f++) xr[f] = fmaxf(x1[(size_t)j * NF1 + f], 0.0f);
    float d = dinv[j];
#pragma unroll
    for (int c = 0; c < NF2; c++) {
        float acc = 0.0f;
#pragma unroll
        for (int f = 0; f < NF1; f++) acc += xr[f] * W2[f * NF2 + c];
        hh[(size_t)j * NF2 + c] = d * acc;
    }
}

// ---------- agg layer 2 + fused log-softmax, per bucket in LDS ----------
__global__ __launch_bounds__(1024) void agg2_lsm_kernel(const ull* __restrict__ pool,
                                                        const int* __restrict__ bbase,
                                                        const float* __restrict__ dinv,
                                                        const float* __restrict__ hh,
                                                        const float* __restrict__ b2,
                                                        float* __restrict__ out, int N) {
    __shared__ float acc[512 * 11];              // stride 11
    int t = threadIdx.x;
    int b = blockIdx.x;
    for (int i = t; i < 512 * 11; i += 1024) acc[i] = 0.0f;
    __syncthreads();
    int bb = bbase[b], be = bbase[b + 1];
    int f = t & 15;
    int eg = t >> 4;
    for (int i = bb + eg; i < be; i += 64) {
        ull p = pool[i];
        unsigned hi = (unsigned)(p >> 32);
        int c9 = (hi >> 20) & 511;
        int r = hi & 0xFFFFF;
        float w = __uint_as_float((unsigned)p);
        if (f < NF2) {
            float hv = hh[(size_t)r * NF2 + f];
            atomicAdd(&acc[c9 * 11 + f], w * hv);
        }
    }
    __syncthreads();
    if (t < 512) {
        int node = (b << 9) + t;
        if (node < N) {
            float di = dinv[node];
            float v[NF2];
            float m = -INFINITY;
#pragma unroll
            for (int c = 0; c < NF2; c++) {
                v[c] = b2[c] + di * (acc[t * 11 + c] + hh[(size_t)node * NF2 + c]);
                m = fmaxf(m, v[c]);
            }
            float s = 0.0f;
#pragma unroll
            for (int c = 0; c < NF2; c++) s += expf(v[c] - m);
            float ls = logf(s);
#pragma unroll
            for (int c = 0; c < NF2; c++) acc[t * 11 + c] = v[c] - m - ls;
        }
    }
    __syncthreads();
    for (int idx = t; idx < 512 * NF2; idx += 1024) {
        int c9 = idx / NF2, c = idx - c9 * NF2;
        int node = (b << 9) + c9;
        if (node < N) out[(size_t)node * NF2 + c] = acc[c9 * 11 + c];
    }
}

extern "C" void kernel_launch(void* const* d_in, const int* in_sizes, int n_in,
                              void* d_out, int out_size, void* d_ws, size_t ws_size,
                              hipStream_t stream) {
    const float* x  = (const float*)d_in[0];
    const int*   ei = (const int*)d_in[1];
    const float* ew = (const float*)d_in[2];
    const float* W1 = (const float*)d_in[3];
    const float* b1 = (const float*)d_in[4];
    const float* W2 = (const float*)d_in[5];
    const float* b2 = (const float*)d_in[6];

    const int E = in_sizes[2];           // 3,200,000
    const int N = in_sizes[0] / FIN;     // 100,000
    const int* row = ei;
    const int* col = ei + E;

    const int NB   = (N + 511) >> 9;     // coarse buckets (196)
    const int NBLK = (E + EPB - 1) / EPB;

    float* out    = (float*)d_out;
    float* logits = out;                        // [N,10]
    float* x1     = out + (size_t)N * NF2;      // [N,16]

    char* ws = (char*)d_ws;
    size_t off = 0;
    auto alloc = [&](size_t bytes) { void* p = ws + off; off += (bytes + 255) / 256 * 256; return p; };
    ull*   pool    = (ull*)  alloc((size_t)E * 8);
    float* part    = (float*)alloc((size_t)SK * N * NF1 * 4);  // split-K partials
    float* hs      = (float*)alloc((size_t)N * NF1 * 4);       // dinv*(x@W1)
    float* hh      = (float*)alloc((size_t)N * NF2 * 4 + 64);  // dinv*relu(x1)@W2
    float* dinv    = (float*)alloc((size_t)N * 4);
    int*   blkhist = (int*)  alloc((size_t)NB * NBLK * 4);
    int*   btot    = (int*)  alloc((size_t)NB * 4);
    int*   bbase   = (int*)  alloc((size_t)(NB + 1) * 4);
    (void)ws_size; (void)n_in; (void)out_size;

    dim3 blk(256);
    int gN    = (N + 255) / 256;
    int nbRow = (N + 255) / 256;         // gemm1 row-blocks per K-quarter

    // build bucket-ordered edge pool (zero global atomics)
    coarse_count_kernel<<<NBLK, blk, 0, stream>>>(col, blkhist, E, NB, NBLK);
    bucket_scan_kernel<<<NB, dim3(512), 0, stream>>>(blkhist, btot, NBLK);
    base_scan_kernel<<<1, blk, 0, stream>>>(btot, bbase, NB, E);
    coarse_scatter_kernel<<<NBLK, blk, 0, stream>>>(row, col, ew, blkhist, bbase, pool, E, NB, NBLK);
    bucket_deg_kernel<<<NB, dim3(1024), 0, stream>>>(pool, bbase, dinv, N);

    // layer 1
    gemm1_kernel<<<SK * nbRow, blk, 0, stream>>>(x, W1, part, N, nbRow);
    combine_scale_kernel<<<(N * NF1 / 4 + 255) / 256, blk, 0, stream>>>(part, dinv, hs, N);
    agg1_kernel<<<NB, dim3(1024), 0, stream>>>(pool, bbase, dinv, hs, b1, x1, N);

    // layer 2
    gemm2_kernel<<<gN, blk, 0, stream>>>(x1, W2, dinv, hh, N);
    agg2_lsm_kernel<<<NB, dim3(1024), 0, stream>>>(pool, bbase, dinv, hh, b2, logits, N);
}

// Round 10
// 305.574 us; speedup vs baseline: 2.4895x; 2.4895x over previous
//
#include <hip/hip_runtime.h>
#include <hip/hip_bf16.h>

// GCN 2-layer forward on MI355X — round 10 = round-8 structure (best: 305us)
// + gemm1 split-K=4 (the only validated round-9 change; the bucket-LDS agg
// experiment regressed 2.5x — 196 blocks was latency-bound serial walking —
// and is reverted to fine-sorted CSR + 16-thread-per-node gathers).
// Inputs: x[N,512] f32, edge_index[2,E] int32, edge_weight[E] f32,
//         W1[512,16], b1[16], W2[16,10], b2[10]
// Outputs (concat): log_softmax(logits)[N,10], x1[N,16]

#define NF1 16   // hidden
#define NF2 10   // classes
#define FIN 512
#define EPB 8192 // edges per coarse block (256 thr * 32)
#define SK  4    // gemm1 split-K factor

typedef unsigned long long ull;

// ---------- A: coarse count (col>>9) into per-block histograms ----------
__global__ __launch_bounds__(256) void coarse_count_kernel(const int* __restrict__ col,
                                                           int* __restrict__ blkhist,
                                                           int E, int NB, int NBLK) {
    __shared__ int lh[256];
    int t = threadIdx.x;
    lh[t] = 0;
    __syncthreads();
    int base = blockIdx.x * EPB;
    int cnt = min(EPB, E - base);
    for (int i = t; i < cnt; i += 256)
        atomicAdd(&lh[col[base + i] >> 9], 1);
    __syncthreads();
    if (t < NB) blkhist[t * NBLK + blockIdx.x] = lh[t];
}

// ---------- B1: per-bucket exclusive scan over blocks (parallel) ----------
__global__ __launch_bounds__(512) void bucket_scan_kernel(int* __restrict__ blkhist,
                                                          int* __restrict__ btot,
                                                          int NBLK) {
    __shared__ int s[512];
    int t = threadIdx.x;
    int* p = blkhist + (size_t)blockIdx.x * NBLK;
    int carry = 0;
    for (int base = 0; base < NBLK; base += 512) {
        int idx = base + t;
        int v = (idx < NBLK) ? p[idx] : 0;
        s[t] = v;
        __syncthreads();
        for (int off = 1; off < 512; off <<= 1) {
            int u = (t >= off) ? s[t - off] : 0;
            __syncthreads();
            s[t] += u;
            __syncthreads();
        }
        if (idx < NBLK) p[idx] = s[t] - v + carry;
        carry += s[511];
        __syncthreads();
    }
    if (t == 0) btot[blockIdx.x] = carry;
}

// ---------- B2: scan bucket totals -> bbase ----------
__global__ __launch_bounds__(256) void base_scan_kernel(const int* __restrict__ btot,
                                                        int* __restrict__ bbase,
                                                        int* __restrict__ rowptr,
                                                        int NB, int E, int N) {
    __shared__ int s[256];
    int t = threadIdx.x;
    int v = (t < NB) ? btot[t] : 0;
    s[t] = v;
    __syncthreads();
    for (int off = 1; off < 256; off <<= 1) {
        int u = (t >= off) ? s[t - off] : 0;
        __syncthreads();
        s[t] += u;
        __syncthreads();
    }
    if (t < NB) bbase[t] = s[t] - v;
    if (t == 0) { bbase[NB] = E; rowptr[N] = E; }
}

// ---------- C: coarse scatter into bucket-ordered pool ----------
// pool entry: hi32 = (c9<<20)|row, lo32 = weight bits
__global__ __launch_bounds__(256) void coarse_scatter_kernel(const int* __restrict__ row,
                                                             const int* __restrict__ col,
                                                             const float* __restrict__ ew,
                                                             const int* __restrict__ blkhist,
                                                             const int* __restrict__ bbase,
                                                             ull* __restrict__ pool,
                                                             int E, int NB, int NBLK) {
    __shared__ int cur[256];
    int t = threadIdx.x;
    if (t < NB) cur[t] = blkhist[t * NBLK + blockIdx.x] + bbase[t];
    __syncthreads();
    int base = blockIdx.x * EPB;
    int cnt = min(EPB, E - base);
    for (int i = t; i < cnt; i += 256) {
        int e = base + i;
        int c = col[e], r = row[e];
        float w = ew[e];
        int b = c >> 9, c9 = c & 511;
        int pos = atomicAdd(&cur[b], 1);
        pool[pos] = ((ull)((((unsigned)c9) << 20) | (unsigned)r) << 32) | (ull)__float_as_uint(w);
    }
}

// ---------- D: fine sort within bucket (512 cols) -> CSR (raw w), rowptr, dinv ----------
__global__ __launch_bounds__(1024) void fine_sort_kernel(const ull* __restrict__ pool,
                                                         const int* __restrict__ bbase,
                                                         ull* __restrict__ csr,
                                                         int* __restrict__ rowptr,
                                                         float* __restrict__ dinv, int N) {
    __shared__ int hist[512];
    __shared__ float wsum[512];
    __shared__ int cur[512];
    int t = threadIdx.x;
    int b = blockIdx.x;
    int bb = bbase[b], be = bbase[b + 1];
    int Ki = be - bb;
    if (t < 512) { hist[t] = 0; wsum[t] = 0.0f; }
    __syncthreads();
    for (int i = t; i < Ki; i += 1024) {
        ull p = pool[bb + i];
        unsigned hi = (unsigned)(p >> 32);
        int c9 = (hi >> 20) & 511;
        atomicAdd(&hist[c9], 1);
        atomicAdd(&wsum[c9], __uint_as_float((unsigned)p));
    }
    __syncthreads();
    int own = (t < 512) ? hist[t] : 0;
    if (t < 512) cur[t] = own;
    __syncthreads();
    for (int off = 1; off < 512; off <<= 1) {
        int v = (t >= off && t < 512) ? cur[t - off] : 0;
        __syncthreads();
        if (t < 512) cur[t] += v;
        __syncthreads();
    }
    int excl = (t < 512) ? (cur[t] - own) : 0;
    if (t < 512) cur[t] = excl;
    int c = (b << 9) + t;
    if (t < 512 && c < N) {
        rowptr[c] = bb + excl;
        dinv[c] = rsqrtf(1.0f + wsum[t]);       // deg = self(1) + sum(w)
    }
    __syncthreads();
    for (int i = t; i < Ki; i += 1024) {
        ull p = pool[bb + i];
        unsigned hi = (unsigned)(p >> 32);
        int c9 = (hi >> 20) & 511;
        unsigned r = hi & 0xFFFFFu;
        int k = atomicAdd(&cur[c9], 1);
        csr[bb + k] = ((p & 0xFFFFFFFFull) << 32) | (ull)r;   // raw weight
    }
}

// ---------- GEMM1 (split-K=4, no LDS, full-line loads): part[q][row][f] ----------
__device__ __forceinline__ void fma16(float av, const float* __restrict__ wrow,
                                      float* __restrict__ acc) {
#pragma unroll
    for (int f = 0; f < NF1; f++) acc[f] = fmaf(av, wrow[f], acc[f]);
}

__global__ __launch_bounds__(256) void gemm1_kernel(const float* __restrict__ x,
                                                    const float* __restrict__ W1,
                                                    float* __restrict__ part,
                                                    int N, int nbRow) {
    int b = blockIdx.x;
    int q = b / nbRow;                 // K-quarter 0..3
    int rb = b - q * nbRow;
    int row = rb * 256 + threadIdx.x;
    if (row >= N) return;
    const int k0 = q * (FIN / SK);     // 128 per quarter

    float acc[NF1];
#pragma unroll
    for (int f = 0; f < NF1; f++) acc[f] = 0.0f;

    const float* xr = x + (size_t)row * FIN + k0;
    const float* wp = W1 + (size_t)k0 * NF1;

#pragma unroll 2
    for (int k = 0; k < FIN / SK; k += 16) {
        const float4* xp = reinterpret_cast<const float4*>(xr + k);
        float4 a0 = xp[0];
        float4 a1 = xp[1];
        float4 a2 = xp[2];
        float4 a3 = xp[3];
        const float* wk = wp + (size_t)k * NF1;
        fma16(a0.x, wk + 0 * NF1, acc);
        fma16(a0.y, wk + 1 * NF1, acc);
        fma16(a0.z, wk + 2 * NF1, acc);
        fma16(a0.w, wk + 3 * NF1, acc);
        fma16(a1.x, wk + 4 * NF1, acc);
        fma16(a1.y, wk + 5 * NF1, acc);
        fma16(a1.z, wk + 6 * NF1, acc);
        fma16(a1.w, wk + 7 * NF1, acc);
        fma16(a2.x, wk + 8 * NF1, acc);
        fma16(a2.y, wk + 9 * NF1, acc);
        fma16(a2.z, wk + 10 * NF1, acc);
        fma16(a2.w, wk + 11 * NF1, acc);
        fma16(a3.x, wk + 12 * NF1, acc);
        fma16(a3.y, wk + 13 * NF1, acc);
        fma16(a3.z, wk + 14 * NF1, acc);
        fma16(a3.w, wk + 15 * NF1, acc);
    }

    float* pp = part + ((size_t)q * N + row) * NF1;
#pragma unroll
    for (int qq = 0; qq < 4; qq++) {
        float4 o = make_float4(acc[4 * qq], acc[4 * qq + 1], acc[4 * qq + 2], acc[4 * qq + 3]);
        *reinterpret_cast<float4*>(pp + 4 * qq) = o;
    }
}

// ---------- combine split-K partials, fold dinv: hs = dinv[row]*(p0+p1+p2+p3) ----------
__global__ __launch_bounds__(256) void combine_scale_kernel(const float* __restrict__ part,
                                                            const float* __restrict__ dinv,
                                                            float* __restrict__ hs, int N) {
    int i4 = blockIdx.x * 256 + threadIdx.x;     // float4 index
    int total = N * NF1 / 4;
    if (i4 >= total) return;
    int rowIdx = i4 >> 2;                        // 4 float4 per row
    const float4* p0 = reinterpret_cast<const float4*>(part);
    const float4* p1 = reinterpret_cast<const float4*>(part + (size_t)1 * N * NF1);
    const float4* p2 = reinterpret_cast<const float4*>(part + (size_t)2 * N * NF1);
    const float4* p3 = reinterpret_cast<const float4*>(part + (size_t)3 * N * NF1);
    float4 a = p0[i4], b = p1[i4], c = p2[i4], d4 = p3[i4];
    float d = dinv[rowIdx];
    float4 o = make_float4(d * (a.x + b.x + c.x + d4.x), d * (a.y + b.y + c.y + d4.y),
                           d * (a.z + b.z + c.z + d4.z), d * (a.w + b.w + c.w + d4.w));
    reinterpret_cast<float4*>(hs)[i4] = o;
}

// ---------- gather layer 1: x1[c] = b1 + di*( sum ew_i*h'[r_i] + h'[c] ) ----------
__global__ __launch_bounds__(256) void gather1_kernel(const ull* __restrict__ csr,
                                                      const int* __restrict__ rowptr,
                                                      const float* __restrict__ dinv,
                                                      const float* __restrict__ hs,
                                                      const float* __restrict__ b1,
                                                      float* __restrict__ x1, int N) {
    int t = blockIdx.x * 256 + threadIdx.x;
    int node = t >> 4, f = t & 15;
    if (node >= N) return;
    int s = rowptr[node], e = rowptr[node + 1];
    float di = dinv[node];
    float acc = hs[(size_t)node * NF1 + f];       // self-loop: h'[c]
    int i = s;
    for (; i + 1 < e; i += 2) {
        ull v0 = csr[i], v1 = csr[i + 1];
        int r0 = (int)(v0 & 0xffffffffull); float w0 = __uint_as_float((unsigned)(v0 >> 32));
        int r1 = (int)(v1 & 0xffffffffull); float w1 = __uint_as_float((unsigned)(v1 >> 32));
        acc += w0 * hs[(size_t)r0 * NF1 + f];
        acc += w1 * hs[(size_t)r1 * NF1 + f];
    }
    if (i < e) {
        ull v = csr[i];
        int r = (int)(v & 0xffffffffull); float w = __uint_as_float((unsigned)(v >> 32));
        acc += w * hs[(size_t)r * NF1 + f];
    }
    x1[(size_t)node * NF1 + f] = b1[f] + di * acc;
}

// ---------- GEMM2: hh' = dinv[j] * (relu(x1[j]) @ W2) ----------
__global__ __launch_bounds__(256) void gemm2_kernel(const float* __restrict__ x1,
                                                    const float* __restrict__ W2,
                                                    const float* __restrict__ dinv,
                                                    float* __restrict__ hh, int N) {
    int j = blockIdx.x * 256 + threadIdx.x;
    if (j >= N) return;
    float xr[NF1];
#pragma unroll
    for (int f = 0; f < NF1; f++) xr[f] = fmaxf(x1[(size_t)j * NF1 + f], 0.0f);
    float d = dinv[j];
#pragma unroll
    for (int c = 0; c < NF2; c++) {
        float acc = 0.0f;
#pragma unroll
        for (int f = 0; f < NF1; f++) acc += xr[f] * W2[f * NF2 + c];
        hh[(size_t)j * NF2 + c] = d * acc;
    }
}

// ---------- gather layer 2 + fused log-softmax ----------
__global__ __launch_bounds__(256) void gather2_lsm_kernel(const ull* __restrict__ csr,
                                                          const int* __restrict__ rowptr,
                                                          const float* __restrict__ dinv,
                                                          const float* __restrict__ hh,
                                                          const float* __restrict__ b2,
                                                          float* __restrict__ out, int N) {
    int t = blockIdx.x * 256 + threadIdx.x;
    int node = t >> 4, f = t & 15;
    bool act = (node < N) && (f < NF2);
    float acc = 0.0f;
    if (node < N) {
        int s = rowptr[node], e = rowptr[node + 1];
        float di = dinv[node];
        acc = act ? hh[(size_t)node * NF2 + f] : 0.0f;   // self-loop: hh'[c]
        int i = s;
        for (; i + 1 < e; i += 2) {
            ull v0 = csr[i], v1 = csr[i + 1];
            int r0 = (int)(v0 & 0xffffffffull); float w0 = __uint_as_float((unsigned)(v0 >> 32));
            int r1 = (int)(v1 & 0xffffffffull); float w1 = __uint_as_float((unsigned)(v1 >> 32));
            float h0 = (f < NF2) ? hh[(size_t)r0 * NF2 + f] : 0.0f;
            float h1 = (f < NF2) ? hh[(size_t)r1 * NF2 + f] : 0.0f;
            acc += w0 * h0 + w1 * h1;
        }
        if (i < e) {
            ull v = csr[i];
            int r = (int)(v & 0xffffffffull); float w = __uint_as_float((unsigned)(v >> 32));
            float hv = (f < NF2) ? hh[(size_t)r * NF2 + f] : 0.0f;
            acc += w * hv;
        }
        acc = b2[f] + di * acc;
    }
    // log-softmax across the 16-lane group (10 active lanes)
    float m = act ? acc : -INFINITY;
#pragma unroll
    for (int off = 1; off < 16; off <<= 1) m = fmaxf(m, __shfl_xor(m, off, 16));
    float p = act ? expf(acc - m) : 0.0f;
    float ssum = p;
#pragma unroll
    for (int off = 1; off < 16; off <<= 1) ssum += __shfl_xor(ssum, off, 16);
    if (act) out[(size_t)node * NF2 + f] = acc - m - logf(ssum);
}

extern "C" void kernel_launch(void* const* d_in, const int* in_sizes, int n_in,
                              void* d_out, int out_size, void* d_ws, size_t ws_size,
                              hipStream_t stream) {
    const float* x  = (const float*)d_in[0];
    const int*   ei = (const int*)d_in[1];
    const float* ew = (const float*)d_in[2];
    const float* W1 = (const float*)d_in[3];
    const float* b1 = (const float*)d_in[4];
    const float* W2 = (const float*)d_in[5];
    const float* b2 = (const float*)d_in[6];

    const int E = in_sizes[2];           // 3,200,000
    const int N = in_sizes[0] / FIN;     // 100,000
    const int* row = ei;
    const int* col = ei + E;

    const int NB   = (N + 511) >> 9;     // coarse buckets (196)
    const int NBLK = (E + EPB - 1) / EPB;

    float* out    = (float*)d_out;
    float* logits = out;                        // [N,10]
    float* x1     = out + (size_t)N * NF2;      // [N,16]

    char* ws = (char*)d_ws;
    size_t off = 0;
    auto alloc = [&](size_t bytes) { void* p = ws + off; off += (bytes + 255) / 256 * 256; return p; };
    ull*   pool    = (ull*)  alloc((size_t)E * 8);
    ull*   csr     = (ull*)  alloc((size_t)E * 8);
    float* part    = (float*)alloc((size_t)SK * N * NF1 * 4);  // split-K partials
    float* hs      = (float*)alloc((size_t)N * NF1 * 4);       // dinv*(x@W1)
    float* hh      = (float*)alloc((size_t)N * NF2 * 4 + 64);  // dinv*relu(x1)@W2
    float* dinv    = (float*)alloc((size_t)N * 4);
    int*   rowptr  = (int*)  alloc((size_t)(N + 1) * 4);
    int*   blkhist = (int*)  alloc((size_t)NB * NBLK * 4);
    int*   btot    = (int*)  alloc((size_t)NB * 4);
    int*   bbase   = (int*)  alloc((size_t)(NB + 1) * 4);
    (void)ws_size; (void)n_in; (void)out_size;

    dim3 blk(256);
    int gN    = (N + 255) / 256;
    int g16   = (N + 15) / 16;
    int nbRow = (N + 255) / 256;         // gemm1 row-blocks per K-quarter

    // build CSR (no global atomics)
    coarse_count_kernel<<<NBLK, blk, 0, stream>>>(col, blkhist, E, NB, NBLK);
    bucket_scan_kernel<<<NB, dim3(512), 0, stream>>>(blkhist, btot, NBLK);
    base_scan_kernel<<<1, blk, 0, stream>>>(btot, bbase, rowptr, NB, E, N);
    coarse_scatter_kernel<<<NBLK, blk, 0, stream>>>(row, col, ew, blkhist, bbase, pool, E, NB, NBLK);
    fine_sort_kernel<<<NB, dim3(1024), 0, stream>>>(pool, bbase, csr, rowptr, dinv, N);

    // layer 1
    gemm1_kernel<<<SK * nbRow, blk, 0, stream>>>(x, W1, part, N, nbRow);
    combine_scale_kernel<<<(N * NF1 / 4 + 255) / 256, blk, 0, stream>>>(part, dinv, hs, N);
    gather1_kernel<<<g16, blk, 0, stream>>>(csr, rowptr, dinv, hs, b1, x1, N);

    // layer 2
    gemm2_kernel<<<gN, blk, 0, stream>>>(x1, W2, dinv, hh, N);
    gather2_lsm_kernel<<<g16, blk, 0, stream>>>(csr, rowptr, dinv, hh, b2, logits, N);
}

// Round 11
// 286.422 us; speedup vs baseline: 2.6560x; 1.0669x over previous
//
#include <hip/hip_runtime.h>
#include <hip/hip_bf16.h>

// GCN 2-layer forward on MI355X — round 11 = round-10 structure with the
// gathered tables (hs, hh) stored in BF16: hs 6.4->3.2MB (fits per-XCD 4MB L2),
// hh 4->2MB. Per-edge random line traffic halves; accumulation stays f32.
// Outputs remain f32. Build pipeline and gemm1 (split-K=4) unchanged.
// Inputs: x[N,512] f32, edge_index[2,E] int32, edge_weight[E] f32,
//         W1[512,16], b1[16], W2[16,10], b2[10]
// Outputs (concat): log_softmax(logits)[N,10], x1[N,16]

#define NF1 16   // hidden
#define NF2 10   // classes
#define FIN 512
#define EPB 8192 // edges per coarse block (256 thr * 32)
#define SK  4    // gemm1 split-K factor

typedef unsigned long long ull;
typedef unsigned short us;

// bf16 pack/unpack (round-to-nearest-even; data has no NaN)
__device__ __forceinline__ us f2bf(float f) {
    union { float f; unsigned u; } v; v.f = f;
    unsigned r = v.u + 0x7FFFu + ((v.u >> 16) & 1u);
    return (us)(r >> 16);
}
__device__ __forceinline__ float bf2f(us h) {
    union { unsigned u; float f; } v; v.u = ((unsigned)h) << 16;
    return v.f;
}

// ---------- A: coarse count (col>>9) into per-block histograms ----------
__global__ __launch_bounds__(256) void coarse_count_kernel(const int* __restrict__ col,
                                                           int* __restrict__ blkhist,
                                                           int E, int NB, int NBLK) {
    __shared__ int lh[256];
    int t = threadIdx.x;
    lh[t] = 0;
    __syncthreads();
    int base = blockIdx.x * EPB;
    int cnt = min(EPB, E - base);
    for (int i = t; i < cnt; i += 256)
        atomicAdd(&lh[col[base + i] >> 9], 1);
    __syncthreads();
    if (t < NB) blkhist[t * NBLK + blockIdx.x] = lh[t];
}

// ---------- B1: per-bucket exclusive scan over blocks (parallel) ----------
__global__ __launch_bounds__(512) void bucket_scan_kernel(int* __restrict__ blkhist,
                                                          int* __restrict__ btot,
                                                          int NBLK) {
    __shared__ int s[512];
    int t = threadIdx.x;
    int* p = blkhist + (size_t)blockIdx.x * NBLK;
    int carry = 0;
    for (int base = 0; base < NBLK; base += 512) {
        int idx = base + t;
        int v = (idx < NBLK) ? p[idx] : 0;
        s[t] = v;
        __syncthreads();
        for (int off = 1; off < 512; off <<= 1) {
            int u = (t >= off) ? s[t - off] : 0;
            __syncthreads();
            s[t] += u;
            __syncthreads();
        }
        if (idx < NBLK) p[idx] = s[t] - v + carry;
        carry += s[511];
        __syncthreads();
    }
    if (t == 0) btot[blockIdx.x] = carry;
}

// ---------- B2: scan bucket totals -> bbase ----------
__global__ __launch_bounds__(256) void base_scan_kernel(const int* __restrict__ btot,
                                                        int* __restrict__ bbase,
                                                        int* __restrict__ rowptr,
                                                        int NB, int E, int N) {
    __shared__ int s[256];
    int t = threadIdx.x;
    int v = (t < NB) ? btot[t] : 0;
    s[t] = v;
    __syncthreads();
    for (int off = 1; off < 256; off <<= 1) {
        int u = (t >= off) ? s[t - off] : 0;
        __syncthreads();
        s[t] += u;
        __syncthreads();
    }
    if (t < NB) bbase[t] = s[t] - v;
    if (t == 0) { bbase[NB] = E; rowptr[N] = E; }
}

// ---------- C: coarse scatter into bucket-ordered pool ----------
// pool entry: hi32 = (c9<<20)|row, lo32 = weight bits
__global__ __launch_bounds__(256) void coarse_scatter_kernel(const int* __restrict__ row,
                                                             const int* __restrict__ col,
                                                             const float* __restrict__ ew,
                                                             const int* __restrict__ blkhist,
                                                             const int* __restrict__ bbase,
                                                             ull* __restrict__ pool,
                                                             int E, int NB, int NBLK) {
    __shared__ int cur[256];
    int t = threadIdx.x;
    if (t < NB) cur[t] = blkhist[t * NBLK + blockIdx.x] + bbase[t];
    __syncthreads();
    int base = blockIdx.x * EPB;
    int cnt = min(EPB, E - base);
    for (int i = t; i < cnt; i += 256) {
        int e = base + i;
        int c = col[e], r = row[e];
        float w = ew[e];
        int b = c >> 9, c9 = c & 511;
        int pos = atomicAdd(&cur[b], 1);
        pool[pos] = ((ull)((((unsigned)c9) << 20) | (unsigned)r) << 32) | (ull)__float_as_uint(w);
    }
}

// ---------- D: fine sort within bucket (512 cols) -> CSR (raw w), rowptr, dinv ----------
__global__ __launch_bounds__(1024) void fine_sort_kernel(const ull* __restrict__ pool,
                                                         const int* __restrict__ bbase,
                                                         ull* __restrict__ csr,
                                                         int* __restrict__ rowptr,
                                                         float* __restrict__ dinv, int N) {
    __shared__ int hist[512];
    __shared__ float wsum[512];
    __shared__ int cur[512];
    int t = threadIdx.x;
    int b = blockIdx.x;
    int bb = bbase[b], be = bbase[b + 1];
    int Ki = be - bb;
    if (t < 512) { hist[t] = 0; wsum[t] = 0.0f; }
    __syncthreads();
    for (int i = t; i < Ki; i += 1024) {
        ull p = pool[bb + i];
        unsigned hi = (unsigned)(p >> 32);
        int c9 = (hi >> 20) & 511;
        atomicAdd(&hist[c9], 1);
        atomicAdd(&wsum[c9], __uint_as_float((unsigned)p));
    }
    __syncthreads();
    int own = (t < 512) ? hist[t] : 0;
    if (t < 512) cur[t] = own;
    __syncthreads();
    for (int off = 1; off < 512; off <<= 1) {
        int v = (t >= off && t < 512) ? cur[t - off] : 0;
        __syncthreads();
        if (t < 512) cur[t] += v;
        __syncthreads();
    }
    int excl = (t < 512) ? (cur[t] - own) : 0;
    if (t < 512) cur[t] = excl;
    int c = (b << 9) + t;
    if (t < 512 && c < N) {
        rowptr[c] = bb + excl;
        dinv[c] = rsqrtf(1.0f + wsum[t]);       // deg = self(1) + sum(w)
    }
    __syncthreads();
    for (int i = t; i < Ki; i += 1024) {
        ull p = pool[bb + i];
        unsigned hi = (unsigned)(p >> 32);
        int c9 = (hi >> 20) & 511;
        unsigned r = hi & 0xFFFFFu;
        int k = atomicAdd(&cur[c9], 1);
        csr[bb + k] = ((p & 0xFFFFFFFFull) << 32) | (ull)r;   // raw weight
    }
}

// ---------- GEMM1 (split-K=4, no LDS, full-line loads): part[q][row][f] ----------
__device__ __forceinline__ void fma16(float av, const float* __restrict__ wrow,
                                      float* __restrict__ acc) {
#pragma unroll
    for (int f = 0; f < NF1; f++) acc[f] = fmaf(av, wrow[f], acc[f]);
}

__global__ __launch_bounds__(256) void gemm1_kernel(const float* __restrict__ x,
                                                    const float* __restrict__ W1,
                                                    float* __restrict__ part,
                                                    int N, int nbRow) {
    int b = blockIdx.x;
    int q = b / nbRow;                 // K-quarter 0..3
    int rb = b - q * nbRow;
    int row = rb * 256 + threadIdx.x;
    if (row >= N) return;
    const int k0 = q * (FIN / SK);     // 128 per quarter

    float acc[NF1];
#pragma unroll
    for (int f = 0; f < NF1; f++) acc[f] = 0.0f;

    const float* xr = x + (size_t)row * FIN + k0;
    const float* wp = W1 + (size_t)k0 * NF1;

#pragma unroll 2
    for (int k = 0; k < FIN / SK; k += 16) {
        const float4* xp = reinterpret_cast<const float4*>(xr + k);
        float4 a0 = xp[0];
        float4 a1 = xp[1];
        float4 a2 = xp[2];
        float4 a3 = xp[3];
        const float* wk = wp + (size_t)k * NF1;
        fma16(a0.x, wk + 0 * NF1, acc);
        fma16(a0.y, wk + 1 * NF1, acc);
        fma16(a0.z, wk + 2 * NF1, acc);
        fma16(a0.w, wk + 3 * NF1, acc);
        fma16(a1.x, wk + 4 * NF1, acc);
        fma16(a1.y, wk + 5 * NF1, acc);
        fma16(a1.z, wk + 6 * NF1, acc);
        fma16(a1.w, wk + 7 * NF1, acc);
        fma16(a2.x, wk + 8 * NF1, acc);
        fma16(a2.y, wk + 9 * NF1, acc);
        fma16(a2.z, wk + 10 * NF1, acc);
        fma16(a2.w, wk + 11 * NF1, acc);
        fma16(a3.x, wk + 12 * NF1, acc);
        fma16(a3.y, wk + 13 * NF1, acc);
        fma16(a3.z, wk + 14 * NF1, acc);
        fma16(a3.w, wk + 15 * NF1, acc);
    }

    float* pp = part + ((size_t)q * N + row) * NF1;
#pragma unroll
    for (int qq = 0; qq < 4; qq++) {
        float4 o = make_float4(acc[4 * qq], acc[4 * qq + 1], acc[4 * qq + 2], acc[4 * qq + 3]);
        *reinterpret_cast<float4*>(pp + 4 * qq) = o;
    }
}

// ---------- combine split-K partials, fold dinv, pack bf16: hs16 = bf16(dinv*(Σp)) ----------
__global__ __launch_bounds__(256) void combine_scale_kernel(const float* __restrict__ part,
                                                            const float* __restrict__ dinv,
                                                            us* __restrict__ hs16, int N) {
    int i4 = blockIdx.x * 256 + threadIdx.x;     // 4-float chunk index
    int total = N * NF1 / 4;
    if (i4 >= total) return;
    int rowIdx = i4 >> 2;                        // 4 chunks per row
    const float4* p0 = reinterpret_cast<const float4*>(part);
    const float4* p1 = reinterpret_cast<const float4*>(part + (size_t)1 * N * NF1);
    const float4* p2 = reinterpret_cast<const float4*>(part + (size_t)2 * N * NF1);
    const float4* p3 = reinterpret_cast<const float4*>(part + (size_t)3 * N * NF1);
    float4 a = p0[i4], b = p1[i4], c = p2[i4], d4 = p3[i4];
    float d = dinv[rowIdx];
    ushort4 u;
    u.x = f2bf(d * (a.x + b.x + c.x + d4.x));
    u.y = f2bf(d * (a.y + b.y + c.y + d4.y));
    u.z = f2bf(d * (a.z + b.z + c.z + d4.z));
    u.w = f2bf(d * (a.w + b.w + c.w + d4.w));
    reinterpret_cast<ushort4*>(hs16)[i4] = u;
}

// ---------- gather layer 1: x1[c] = b1 + di*( sum ew_i*hs[r_i] + hs[c] ) ----------
__global__ __launch_bounds__(256) void gather1_kernel(const ull* __restrict__ csr,
                                                      const int* __restrict__ rowptr,
                                                      const float* __restrict__ dinv,
                                                      const us* __restrict__ hs16,
                                                      const float* __restrict__ b1,
                                                      float* __restrict__ x1, int N) {
    int t = blockIdx.x * 256 + threadIdx.x;
    int node = t >> 4, f = t & 15;
    if (node >= N) return;
    int s = rowptr[node], e = rowptr[node + 1];
    float di = dinv[node];
    float acc = bf2f(hs16[(size_t)node * NF1 + f]);   // self-loop: hs[c]
    int i = s;
    for (; i + 1 < e; i += 2) {
        ull v0 = csr[i], v1 = csr[i + 1];
        int r0 = (int)(v0 & 0xffffffffull); float w0 = __uint_as_float((unsigned)(v0 >> 32));
        int r1 = (int)(v1 & 0xffffffffull); float w1 = __uint_as_float((unsigned)(v1 >> 32));
        acc += w0 * bf2f(hs16[(size_t)r0 * NF1 + f]);
        acc += w1 * bf2f(hs16[(size_t)r1 * NF1 + f]);
    }
    if (i < e) {
        ull v = csr[i];
        int r = (int)(v & 0xffffffffull); float w = __uint_as_float((unsigned)(v >> 32));
        acc += w * bf2f(hs16[(size_t)r * NF1 + f]);
    }
    x1[(size_t)node * NF1 + f] = b1[f] + di * acc;
}

// ---------- GEMM2: hh16 = bf16( dinv[j] * (relu(x1[j]) @ W2) ) ----------
__global__ __launch_bounds__(256) void gemm2_kernel(const float* __restrict__ x1,
                                                    const float* __restrict__ W2,
                                                    const float* __restrict__ dinv,
                                                    us* __restrict__ hh16, int N) {
    int j = blockIdx.x * 256 + threadIdx.x;
    if (j >= N) return;
    float xr[NF1];
#pragma unroll
    for (int f = 0; f < NF1; f++) xr[f] = fmaxf(x1[(size_t)j * NF1 + f], 0.0f);
    float d = dinv[j];
    float o[NF2];
#pragma unroll
    for (int c = 0; c < NF2; c++) {
        float acc = 0.0f;
#pragma unroll
        for (int f = 0; f < NF1; f++) acc += xr[f] * W2[f * NF2 + c];
        o[c] = d * acc;
    }
    // pack 10 bf16 as 5 uints (row offset j*20 B is 4B-aligned)
    unsigned* hp = reinterpret_cast<unsigned*>(const_cast<us*>(hh16) + (size_t)j * NF2);
#pragma unroll
    for (int cp = 0; cp < 5; cp++)
        hp[cp] = (unsigned)f2bf(o[2 * cp]) | ((unsigned)f2bf(o[2 * cp + 1]) << 16);
}

// ---------- gather layer 2 + fused log-softmax ----------
__global__ __launch_bounds__(256) void gather2_lsm_kernel(const ull* __restrict__ csr,
                                                          const int* __restrict__ rowptr,
                                                          const float* __restrict__ dinv,
                                                          const us* __restrict__ hh16,
                                                          const float* __restrict__ b2,
                                                          float* __restrict__ out, int N) {
    int t = blockIdx.x * 256 + threadIdx.x;
    int node = t >> 4, f = t & 15;
    bool act = (node < N) && (f < NF2);
    float acc = 0.0f;
    if (node < N) {
        int s = rowptr[node], e = rowptr[node + 1];
        float di = dinv[node];
        acc = act ? bf2f(hh16[(size_t)node * NF2 + f]) : 0.0f;   // self-loop
        int i = s;
        for (; i + 1 < e; i += 2) {
            ull v0 = csr[i], v1 = csr[i + 1];
            int r0 = (int)(v0 & 0xffffffffull); float w0 = __uint_as_float((unsigned)(v0 >> 32));
            int r1 = (int)(v1 & 0xffffffffull); float w1 = __uint_as_float((unsigned)(v1 >> 32));
            float h0 = (f < NF2) ? bf2f(hh16[(size_t)r0 * NF2 + f]) : 0.0f;
            float h1 = (f < NF2) ? bf2f(hh16[(size_t)r1 * NF2 + f]) : 0.0f;
            acc += w0 * h0 + w1 * h1;
        }
        if (i < e) {
            ull v = csr[i];
            int r = (int)(v & 0xffffffffull); float w = __uint_as_float((unsigned)(v >> 32));
            float hv = (f < NF2) ? bf2f(hh16[(size_t)r * NF2 + f]) : 0.0f;
            acc += w * hv;
        }
        acc = b2[f] + di * acc;
    }
    // log-softmax across the 16-lane group (10 active lanes)
    float m = act ? acc : -INFINITY;
#pragma unroll
    for (int off = 1; off < 16; off <<= 1) m = fmaxf(m, __shfl_xor(m, off, 16));
    float p = act ? expf(acc - m) : 0.0f;
    float ssum = p;
#pragma unroll
    for (int off = 1; off < 16; off <<= 1) ssum += __shfl_xor(ssum, off, 16);
    if (act) out[(size_t)node * NF2 + f] = acc - m - logf(ssum);
}

extern "C" void kernel_launch(void* const* d_in, const int* in_sizes, int n_in,
                              void* d_out, int out_size, void* d_ws, size_t ws_size,
                              hipStream_t stream) {
    const float* x  = (const float*)d_in[0];
    const int*   ei = (const int*)d_in[1];
    const float* ew = (const float*)d_in[2];
    const float* W1 = (const float*)d_in[3];
    const float* b1 = (const float*)d_in[4];
    const float* W2 = (const float*)d_in[5];
    const float* b2 = (const float*)d_in[6];

    const int E = in_sizes[2];           // 3,200,000
    const int N = in_sizes[0] / FIN;     // 100,000
    const int* row = ei;
    const int* col = ei + E;

    const int NB   = (N + 511) >> 9;     // coarse buckets (196)
    const int NBLK = (E + EPB - 1) / EPB;

    float* out    = (float*)d_out;
    float* logits = out;                        // [N,10]
    float* x1     = out + (size_t)N * NF2;      // [N,16]

    char* ws = (char*)d_ws;
    size_t off = 0;
    auto alloc = [&](size_t bytes) { void* p = ws + off; off += (bytes + 255) / 256 * 256; return p; };
    ull*   pool    = (ull*)  alloc((size_t)E * 8);
    ull*   csr     = (ull*)  alloc((size_t)E * 8);
    float* part    = (float*)alloc((size_t)SK * N * NF1 * 4);  // split-K partials
    us*    hs16    = (us*)   alloc((size_t)N * NF1 * 2);       // bf16 dinv*(x@W1)
    us*    hh16    = (us*)   alloc((size_t)N * NF2 * 2 + 64);  // bf16 dinv*relu(x1)@W2
    float* dinv    = (float*)alloc((size_t)N * 4);
    int*   rowptr  = (int*)  alloc((size_t)(N + 1) * 4);
    int*   blkhist = (int*)  alloc((size_t)NB * NBLK * 4);
    int*   btot    = (int*)  alloc((size_t)NB * 4);
    int*   bbase   = (int*)  alloc((size_t)(NB + 1) * 4);
    (void)ws_size; (void)n_in; (void)out_size;

    dim3 blk(256);
    int gN    = (N + 255) / 256;
    int g16   = (N + 15) / 16;
    int nbRow = (N + 255) / 256;         // gemm1 row-blocks per K-quarter

    // build CSR (no global atomics)
    coarse_count_kernel<<<NBLK, blk, 0, stream>>>(col, blkhist, E, NB, NBLK);
    bucket_scan_kernel<<<NB, dim3(512), 0, stream>>>(blkhist, btot, NBLK);
    base_scan_kernel<<<1, blk, 0, stream>>>(btot, bbase, rowptr, NB, E, N);
    coarse_scatter_kernel<<<NBLK, blk, 0, stream>>>(row, col, ew, blkhist, bbase, pool, E, NB, NBLK);
    fine_sort_kernel<<<NB, dim3(1024), 0, stream>>>(pool, bbase, csr, rowptr, dinv, N);

    // layer 1
    gemm1_kernel<<<SK * nbRow, blk, 0, stream>>>(x, W1, part, N, nbRow);
    combine_scale_kernel<<<(N * NF1 / 4 + 255) / 256, blk, 0, stream>>>(part, dinv, hs16, N);
    gather1_kernel<<<g16, blk, 0, stream>>>(csr, rowptr, dinv, hs16, b1, x1, N);

    // layer 2
    gemm2_kernel<<<gN, blk, 0, stream>>>(x1, W2, dinv, hh16, N);
    gather2_lsm_kernel<<<g16, blk, 0, stream>>>(csr, rowptr, dinv, hh16, b2, logits, N);
}